// Round 1
// baseline (808.662 us; speedup 1.0000x reference)
//
#include <hip/hip_runtime.h>
#include <hip/hip_bf16.h>
#include <cstdint>
#include <cstddef>

typedef __attribute__((ext_vector_type(8))) short short8;
typedef __attribute__((ext_vector_type(4))) float f32x4;

#define MFMA16(a,b,c) __builtin_amdgcn_mfma_f32_16x16x32_bf16((a),(b),(c),0,0,0)
#define NEG_INF (-__builtin_inff())

__device__ __forceinline__ unsigned short f2bf(float f) {
    union { float f; unsigned int u; } a; a.f = f;
    return (unsigned short)((a.u + 0x7FFFu + ((a.u >> 16) & 1u)) >> 16);
}

// ---------------- elementwise fp32 -> bf16 ----------------
__global__ __launch_bounds__(256) void convert_bf16(const float* __restrict__ src,
                                                    unsigned short* __restrict__ dst, int n) {
    int i = (blockIdx.x * 256 + threadIdx.x) * 4;
    if (i + 3 < n) {
        float4 v = *(const float4*)(src + i);
        ushort4 o;
        o.x = f2bf(v.x); o.y = f2bf(v.y); o.z = f2bf(v.z); o.w = f2bf(v.w);
        *(ushort4*)(dst + i) = o;
    }
}

// ---------------- W (1024x1024 fp32) -> WT (1024x1024 bf16), WT[n][k]=W[k][n] ----------------
__global__ __launch_bounds__(256) void transpose_w(const float* __restrict__ W,
                                                   unsigned short* __restrict__ WT) {
    __shared__ float tile[32][33];
    int tx = threadIdx.x & 31, ty = threadIdx.x >> 5;   // ty 0..7
    int kb = blockIdx.x * 32, nb = blockIdx.y * 32;
    #pragma unroll
    for (int r = 0; r < 32; r += 8)
        tile[ty + r][tx] = W[(size_t)(kb + ty + r) * 1024 + nb + tx];
    __syncthreads();
    #pragma unroll
    for (int r = 0; r < 32; r += 8) {
        float v = tile[tx][ty + r];
        WT[(size_t)(nb + ty + r) * 1024 + kb + tx] = f2bf(v);
    }
}

__global__ __launch_bounds__(256) void pack_bias(const float* __restrict__ bq,
                                                 const float* __restrict__ bk,
                                                 const float* __restrict__ bv,
                                                 float* __restrict__ dst) {
    int i = blockIdx.x * 256 + threadIdx.x;
    if (i < 3072) {
        const float* s = (i < 1024) ? bq : (i < 2048) ? bk : bv;
        dst[i] = s[i & 1023];
    }
}

// ---------------- V [32][2048][64] -> Vt [32][64][2048] (bf16) ----------------
__global__ __launch_bounds__(256) void transpose_v(const unsigned short* __restrict__ V,
                                                   unsigned short* __restrict__ Vt) {
    __shared__ unsigned short tl[64][65];
    int bh = blockIdx.x >> 5;
    int kt = blockIdx.x & 31;
    int t = threadIdx.x;
    int row = t >> 2, off = (t & 3) * 16;
    const unsigned short* src = V + ((size_t)bh * 2048 + kt * 64 + row) * 64 + off;
    uint4 d0 = *(const uint4*)src;
    uint4 d1 = *(const uint4*)(src + 8);
    unsigned short tmp[16];
    *(uint4*)tmp = d0; *(uint4*)(tmp + 8) = d1;
    #pragma unroll
    for (int e = 0; e < 16; e++) tl[row][off + e] = tmp[e];
    __syncthreads();
    int d = t >> 2, ko = (t & 3) * 16;
    unsigned short o[16];
    #pragma unroll
    for (int e = 0; e < 16; e++) o[e] = tl[ko + e][d];
    unsigned short* dst = Vt + ((size_t)bh * 64 + d) * 2048 + kt * 64 + ko;
    *(uint4*)dst = *(uint4*)o;
    *(uint4*)(dst + 8) = *(uint4*)(o + 8);
}

// ---------------- GEMM C = A @ BT^T (+bias), 128x128 tile, bf16 MFMA ----------------
// mode 0: write bf16 into packed QKV [3][B,H,S,64]   mode 1: write fp32 row-major [M][1024]
__global__ __launch_bounds__(256) void gemm_bt(const unsigned short* __restrict__ A,
                                               const unsigned short* __restrict__ BT,
                                               const float* __restrict__ bias,
                                               unsigned short* __restrict__ qkv_out,
                                               float* __restrict__ f32_out,
                                               int mode) {
    __shared__ unsigned short As[128][40];
    __shared__ unsigned short Bs[128][40];
    const int t = threadIdx.x;
    const int wave = t >> 6, lane = t & 63, quad = lane >> 4, l16 = lane & 15;
    const int m0 = blockIdx.x * 128, n0 = blockIdx.y * 128;
    const int wm = (wave >> 1) * 64, wn = (wave & 1) * 64;
    const int srow = t >> 1, soff = (t & 1) * 16;
    f32x4 acc[4][4] = {};
    for (int k0 = 0; k0 < 1024; k0 += 32) {
        __syncthreads();
        const uint4* ga = (const uint4*)(A + (size_t)(m0 + srow) * 1024 + k0 + soff);
        uint4 a0 = ga[0], a1 = ga[1];
        const uint4* gb = (const uint4*)(BT + (size_t)(n0 + srow) * 1024 + k0 + soff);
        uint4 b0 = gb[0], b1 = gb[1];
        *(uint4*)&As[srow][soff] = a0; *(uint4*)&As[srow][soff + 8] = a1;
        *(uint4*)&Bs[srow][soff] = b0; *(uint4*)&Bs[srow][soff + 8] = b1;
        __syncthreads();
        short8 af[4], bfr[4];
        #pragma unroll
        for (int i = 0; i < 4; i++) af[i] = *(const short8*)&As[wm + i * 16 + l16][quad * 8];
        #pragma unroll
        for (int j = 0; j < 4; j++) bfr[j] = *(const short8*)&Bs[wn + j * 16 + l16][quad * 8];
        #pragma unroll
        for (int i = 0; i < 4; i++)
            #pragma unroll
            for (int j = 0; j < 4; j++)
                acc[i][j] = MFMA16(af[i], bfr[j], acc[i][j]);
    }
    #pragma unroll
    for (int i = 0; i < 4; i++) {
        int tokb = m0 + wm + i * 16 + quad * 4;
        #pragma unroll
        for (int j = 0; j < 4; j++) {
            int n = n0 + wn + j * 16 + l16;
            float bv = bias[n];
            #pragma unroll
            for (int r = 0; r < 4; r++) {
                float v = acc[i][j][r] + bv;
                int tok = tokb + r;
                if (mode == 0) {
                    int which = n >> 10, n1 = n & 1023, h = n1 >> 6, d = n1 & 63;
                    int b = tok >> 11, s = tok & 2047;
                    qkv_out[(size_t)which * 4194304 + (((size_t)(b * 16 + h)) * 2048 + s) * 64 + d] = f2bf(v);
                } else {
                    f32_out[(size_t)tok * 1024 + n] = v;
                }
            }
        }
    }
}

// ---------------- fused attention: scores -> softmax -> probs + ctx ----------------
// grid (32 qtiles, 32 bh), 256 threads = 4 waves x 16 q-rows
__global__ __launch_bounds__(256) void attn(const unsigned short* __restrict__ Q,
                                            const unsigned short* __restrict__ K,
                                            const unsigned short* __restrict__ Vt,
                                            const int* __restrict__ amask,
                                            const int* __restrict__ stypes,
                                            const float* __restrict__ script_w,
                                            float* __restrict__ probs,
                                            unsigned short* __restrict__ ctx) {
    __shared__ unsigned short Ks[64][72];
    __shared__ unsigned short Vts[64][72];
    __shared__ unsigned short Ps[4][16][72];
    __shared__ float swl[64];
    __shared__ float mb[64];
    const int t = threadIdx.x;
    const int wave = t >> 6, lane = t & 63, quad = lane >> 4, l16 = lane & 15;
    const int qt = blockIdx.x, bh = blockIdx.y;
    const int b = bh >> 4, h = bh & 15;
    const int q0 = qt * 64;
    if (t < 64) {
        int st = stypes[b * 2048 + q0 + t];
        swl[t] = script_w[st * 16 + h];
    }
    const size_t qbase = ((size_t)bh * 2048 + q0 + wave * 16 + l16) * 64;
    short8 aQ0 = *(const short8*)(Q + qbase + quad * 8);
    short8 aQ1 = *(const short8*)(Q + qbase + 32 + quad * 8);
    const int srow = t >> 2, soff = (t & 3) * 16;

    float mrow[4] = {NEG_INF, NEG_INF, NEG_INF, NEG_INF};
    float lrow[4] = {0.f, 0.f, 0.f, 0.f};

    // ---- pass 1: row max / sumexp ----
    for (int kt = 0; kt < 32; kt++) {
        __syncthreads();
        const unsigned short* ks = K + ((size_t)bh * 2048 + kt * 64 + srow) * 64 + soff;
        uint4 k0 = *(const uint4*)ks, k1 = *(const uint4*)(ks + 8);
        *(uint4*)&Ks[srow][soff] = k0; *(uint4*)&Ks[srow][soff + 8] = k1;
        if (t < 64) mb[t] = amask[b * 2048 + kt * 64 + t] ? 0.0f : NEG_INF;
        __syncthreads();
        f32x4 sc[4] = {};
        #pragma unroll
        for (int j = 0; j < 4; j++) {
            short8 bk0 = *(const short8*)&Ks[j * 16 + l16][quad * 8];
            short8 bk1 = *(const short8*)&Ks[j * 16 + l16][32 + quad * 8];
            sc[j] = MFMA16(aQ0, bk0, sc[j]);
            sc[j] = MFMA16(aQ1, bk1, sc[j]);
        }
        #pragma unroll
        for (int r = 0; r < 4; r++) {
            float sfac = swl[wave * 16 + quad * 4 + r] * 0.125f;
            float s0 = sc[0][r] * sfac + mb[0 + l16];
            float s1 = sc[1][r] * sfac + mb[16 + l16];
            float s2 = sc[2][r] * sfac + mb[32 + l16];
            float s3 = sc[3][r] * sfac + mb[48 + l16];
            float vmax = fmaxf(fmaxf(s0, s1), fmaxf(s2, s3));
            #pragma unroll
            for (int off = 1; off < 16; off <<= 1)
                vmax = fmaxf(vmax, __shfl_xor(vmax, off, 64));
            float mn = fmaxf(mrow[r], vmax);
            if (mn == NEG_INF) continue;   // whole prefix masked; uniform within 16-lane group
            float ps = __expf(s0 - mn) + __expf(s1 - mn) + __expf(s2 - mn) + __expf(s3 - mn);
            #pragma unroll
            for (int off = 1; off < 16; off <<= 1)
                ps += __shfl_xor(ps, off, 64);
            float scale_old = __expf(mrow[r] - mn);
            lrow[r] = lrow[r] * scale_old + ps;
            mrow[r] = mn;
        }
    }
    float inv_l[4];
    #pragma unroll
    for (int r = 0; r < 4; r++) inv_l[r] = (lrow[r] > 0.f) ? 1.0f / lrow[r] : 0.0f;

    // ---- pass 2: recompute, write probs, accumulate ctx ----
    f32x4 oacc[4] = {};
    for (int kt = 0; kt < 32; kt++) {
        __syncthreads();
        const unsigned short* ks = K + ((size_t)bh * 2048 + kt * 64 + srow) * 64 + soff;
        uint4 k0 = *(const uint4*)ks, k1 = *(const uint4*)(ks + 8);
        *(uint4*)&Ks[srow][soff] = k0; *(uint4*)&Ks[srow][soff + 8] = k1;
        const unsigned short* vs = Vt + ((size_t)bh * 64 + srow) * 2048 + kt * 64 + soff;
        uint4 v0 = *(const uint4*)vs, v1 = *(const uint4*)(vs + 8);
        *(uint4*)&Vts[srow][soff] = v0; *(uint4*)&Vts[srow][soff + 8] = v1;
        if (t < 64) mb[t] = amask[b * 2048 + kt * 64 + t] ? 0.0f : NEG_INF;
        __syncthreads();
        f32x4 sc[4] = {};
        #pragma unroll
        for (int j = 0; j < 4; j++) {
            short8 bk0 = *(const short8*)&Ks[j * 16 + l16][quad * 8];
            short8 bk1 = *(const short8*)&Ks[j * 16 + l16][32 + quad * 8];
            sc[j] = MFMA16(aQ0, bk0, sc[j]);
            sc[j] = MFMA16(aQ1, bk1, sc[j]);
        }
        #pragma unroll
        for (int r = 0; r < 4; r++) {
            float sfac = swl[wave * 16 + quad * 4 + r] * 0.125f;
            int qrow = q0 + wave * 16 + quad * 4 + r;
            size_t pbase = ((size_t)bh * 2048 + qrow) * 2048 + kt * 64;
            #pragma unroll
            for (int j = 0; j < 4; j++) {
                float s = sc[j][r] * sfac + mb[j * 16 + l16];
                float p = __expf(s - mrow[r]) * inv_l[r];
                probs[pbase + j * 16 + l16] = p;
                Ps[wave][quad * 4 + r][j * 16 + l16] = f2bf(p);
            }
        }
        __syncthreads();   // make P visible (cross-lane via LDS)
        #pragma unroll
        for (int c = 0; c < 2; c++) {
            short8 aP = *(const short8*)&Ps[wave][l16][c * 32 + quad * 8];
            #pragma unroll
            for (int j2 = 0; j2 < 4; j2++) {
                short8 bV = *(const short8*)&Vts[j2 * 16 + l16][c * 32 + quad * 8];
                oacc[j2] = MFMA16(aP, bV, oacc[j2]);
            }
        }
    }
    #pragma unroll
    for (int j2 = 0; j2 < 4; j2++)
        #pragma unroll
        for (int r = 0; r < 4; r++) {
            int qrow = q0 + wave * 16 + quad * 4 + r;
            ctx[((size_t)b * 2048 + qrow) * 1024 + h * 64 + j2 * 16 + l16] = f2bf(oacc[j2][r]);
        }
}

extern "C" void kernel_launch(void* const* d_in, const int* in_sizes, int n_in,
                              void* d_out, int out_size, void* d_ws, size_t ws_size,
                              hipStream_t stream) {
    const float* X    = (const float*)d_in[0];
    const int*  amask = (const int*)d_in[1];
    const int*  stp   = (const int*)d_in[2];
    const float* Wq   = (const float*)d_in[3];
    const float* bq   = (const float*)d_in[4];
    const float* Wk   = (const float*)d_in[5];
    const float* bk   = (const float*)d_in[6];
    const float* Wv   = (const float*)d_in[7];
    const float* bv   = (const float*)d_in[8];
    const float* Wo   = (const float*)d_in[9];
    const float* bo   = (const float*)d_in[10];
    const float* sw   = (const float*)d_in[11];

    float* out   = (float*)d_out;
    float* probs = out + 4194304;          // (2,16,2048,2048) fp32

    char* ws = (char*)d_ws;
    unsigned short* Xb    = (unsigned short*)(ws);               // 8 MB
    unsigned short* WqkvT = (unsigned short*)(ws + 8388608);     // 6 MB
    unsigned short* WoT   = (unsigned short*)(ws + 14680064);    // 2 MB
    float*          biasq = (float*)(ws + 16777216);             // 12 KB
    unsigned short* Qb    = (unsigned short*)(ws + 16789504);    // 8 MB  (Q,K,V contiguous)
    unsigned short* Vb    = (unsigned short*)(ws + 33566720);
    unsigned short* Vtb   = (unsigned short*)(ws + 41955328);    // 8 MB
    unsigned short* Ctx   = (unsigned short*)(ws + 50343936);    // 8 MB
    unsigned short* Kb    = Qb + 4194304;

    convert_bf16<<<4096, 256, 0, stream>>>(X, Xb, 4194304);
    transpose_w<<<dim3(32, 32), 256, 0, stream>>>(Wq, WqkvT);
    transpose_w<<<dim3(32, 32), 256, 0, stream>>>(Wk, WqkvT + 1048576);
    transpose_w<<<dim3(32, 32), 256, 0, stream>>>(Wv, WqkvT + 2097152);
    transpose_w<<<dim3(32, 32), 256, 0, stream>>>(Wo, WoT);
    pack_bias<<<12, 256, 0, stream>>>(bq, bk, bv, biasq);
    gemm_bt<<<dim3(32, 24), 256, 0, stream>>>(Xb, WqkvT, biasq, Qb, nullptr, 0);
    transpose_v<<<1024, 256, 0, stream>>>(Vb, Vtb);
    attn<<<dim3(32, 32), 256, 0, stream>>>(Qb, Kb, Vtb, amask, stp, sw, probs, Ctx);
    gemm_bt<<<dim3(32, 8), 256, 0, stream>>>(Ctx, WoT, bo, nullptr, out, 1);
}